// Round 13
// baseline (149.898 us; speedup 1.0000x reference)
//
#include <hip/hip_runtime.h>
#include <hip/hip_bf16.h>
#include <hip/hip_fp16.h>
#include <stdint.h>

// GATv2-style layer, MI355X. 4 kernels:
//  k_main:    heterogeneous grid — blocks 0..2047: adj -> bitmask (64 MB HBM
//             stream) + zero stats; blocks 2048..2559: Wh = x @ W^T GEMM
//             (f32 direct-global A/B, in-reg cvt to bf16, MFMA) -> WhT f16
//             (LDS transpose) + factored-softmax arrays Es/es2 f16, r f32.
//             The HBM stream overlaps the L2/MFMA-bound GEMM blocks.
//  k_attn:    fused masked-softmax numer/denom + PV MFMA, f16 packed math:
//             t2 = pk_max(E2, pk_mul(r2, F2)) & mask2 -> f16 A-frag directly.
//             Row factor exp2(b_i) cancels in num/denom. Ring-4 counted-vmcnt
//             global_load_lds prefetch; rolled chunk loop (fits L1i).
//  k_stats:   column sums of h' = (sum num)/(sum accd) via atomics; hp bf16
//  k_apply:   read hp bf16, apply layernorm + relu
// num (16.8 MB bf16, 4 j-slices) lives in the ws overlay region.

typedef __attribute__((ext_vector_type(4))) float f32x4;
typedef __attribute__((ext_vector_type(8))) short s16x8;
typedef __attribute__((ext_vector_type(2))) _Float16 h2v;

#define LOG2E 1.4426950408889634f

static __device__ __forceinline__ short bf16b(float f) {
  __hip_bfloat16 h = __float2bfloat16(f);
  union { __hip_bfloat16 h; short s; } c; c.h = h;
  return c.s;
}

static __device__ __forceinline__ float bf2f(ushort u) {
  union { uint32_t u; float f; } c; c.u = ((uint32_t)u) << 16;
  return c.f;
}

static __device__ __forceinline__ ushort hbits(float f) {
  union { _Float16 h; ushort u; } c; c.h = (_Float16)f;
  return c.u;
}

static __device__ __forceinline__ h2v u2h2(uint32_t u) {
  union { uint32_t u; h2v h; } c; c.u = u; return c.h;
}
static __device__ __forceinline__ uint32_t h22u(h2v h) {
  union { uint32_t u; h2v h; } c; c.h = h; return c.u;
}

// async global->LDS, 16B per lane; dest = wave-uniform base + lane*16
static __device__ __forceinline__ void gl_lds16(const ushort* g, ushort* l) {
  __builtin_amdgcn_global_load_lds(
      (const __attribute__((address_space(1))) unsigned int*)(g),
      (__attribute__((address_space(3))) unsigned int*)(l), 16, 0, 0);
}

// blocks 0..2047: pack adj -> bitmask (+ block 0 zeros stats).
// blocks 2048..2559: 64-row x one-head GEMM, f32 direct loads + in-reg cvt.
__global__ __launch_bounds__(256) void k_main(const float* __restrict__ x,
                                              const float* __restrict__ W,
                                              const int* __restrict__ adj,
                                              const float* __restrict__ a,
                                              unsigned long long* __restrict__ maskw,
                                              float* __restrict__ stats,
                                              ushort* __restrict__ WhT,
                                              ushort* __restrict__ EsT,
                                              ushort* __restrict__ es2T,
                                              float* __restrict__ rT) {
  const int t = threadIdx.x;
  if (blockIdx.x < 2048) {
    // ---------------- pack section (HBM-stream) ----------------
    const int pb = blockIdx.x;
    if (pb == 0) {
      stats[t] = 0.f; stats[t + 256] = 0.f; stats[t + 512] = 0.f; stats[t + 768] = 0.f;
    }
    const size_t base = (size_t)pb * 8192;
    const int lane = t & 63;
#pragma unroll 4
    for (int it = 0; it < 32; ++it) {
      const size_t elem = base + it * 256 + t;
      unsigned long long b = __ballot(adj[elem] > 0);
      if (lane == 0) maskw[elem >> 6] = b;
    }
    return;
  }
  // ---------------- gemm section (L2/MFMA) ----------------
  __shared__ float tl[64 * 65];          // 16.6 KB transpose buffer
  const int g = blockIdx.x - 2048;
  const int lane = t & 63;
  const int wv = t >> 6;                 // 4 waves: M sub-tiles
  const int l15 = lane & 15, lg = lane >> 4;
  const int m0 = (g & 63) * 64;
  const int h = g >> 6;
  const int n0 = h * 64;

  const float* apf = x + (size_t)(m0 + wv * 16 + l15) * 512 + lg * 8;
  f32x4 acc[4] = {};
  for (int k0 = 0; k0 < 512; k0 += 32) {
    float4 a0 = *(const float4*)(apf + k0);
    float4 a1 = *(const float4*)(apf + k0 + 4);
    s16x8 av;
    av[0] = bf16b(a0.x); av[1] = bf16b(a0.y); av[2] = bf16b(a0.z); av[3] = bf16b(a0.w);
    av[4] = bf16b(a1.x); av[5] = bf16b(a1.y); av[6] = bf16b(a1.z); av[7] = bf16b(a1.w);
#pragma unroll
    for (int ct = 0; ct < 4; ++ct) {
      const float* bpf = W + (size_t)(n0 + ct * 16 + l15) * 512 + k0 + lg * 8;
      float4 b0 = *(const float4*)(bpf);
      float4 b1 = *(const float4*)(bpf + 4);
      s16x8 bv;
      bv[0] = bf16b(b0.x); bv[1] = bf16b(b0.y); bv[2] = bf16b(b0.z); bv[3] = bf16b(b0.w);
      bv[4] = bf16b(b1.x); bv[5] = bf16b(b1.y); bv[6] = bf16b(b1.z); bv[7] = bf16b(b1.w);
      acc[ct] = __builtin_amdgcn_mfma_f32_16x16x32_bf16(av, bv, acc[ct], 0, 0, 0);
    }
  }
  // ---- svec: s[row] = sum_col acc*a_slice, reduce over 16 l15 lanes ----
  float aS[4], aD[4];
#pragma unroll
  for (int ct = 0; ct < 4; ++ct) {
    aS[ct] = a[ct * 16 + l15];
    aD[ct] = a[64 + ct * 16 + l15];
  }
#pragma unroll
  for (int r = 0; r < 4; ++r) {
    float s1 = acc[0][r] * aS[0] + acc[1][r] * aS[1] + acc[2][r] * aS[2] + acc[3][r] * aS[3];
    float s2 = acc[0][r] * aD[0] + acc[1][r] * aD[1] + acc[2][r] * aD[2] + acc[3][r] * aD[3];
#pragma unroll
    for (int off = 1; off < 16; off <<= 1) {
      s1 += __shfl_xor(s1, off);
      s2 += __shfl_xor(s2, off);
    }
    if (l15 == 0) {
      const int row = m0 + wv * 16 + lg * 4 + r;
      const float aa = s1 * LOG2E;   // src (j-role), log2 domain
      const float bb = s2 * LOG2E;   // dst (i-role)
      EsT[h * 4096 + row]  = hbits(__builtin_amdgcn_exp2f(aa));
      es2T[h * 4096 + row] = hbits(__builtin_amdgcn_exp2f(0.2f * aa));
      rT[h * 4096 + row]   = __builtin_amdgcn_exp2f(-0.8f * bb);
    }
  }
  // ---- transposed f16 store: WhT[n0+c][m0+m] ----
#pragma unroll
  for (int ct = 0; ct < 4; ++ct)
#pragma unroll
    for (int r = 0; r < 4; ++r)
      tl[(ct * 16 + l15) * 65 + wv * 16 + lg * 4 + r] = acc[ct][r];
  __syncthreads();
  const int c = t >> 2, mb = (t & 3) * 16;
  s16x8 o0, o1;
#pragma unroll
  for (int k = 0; k < 8; ++k) o0[k] = (short)hbits(tl[c * 65 + mb + k]);
#pragma unroll
  for (int k = 0; k < 8; ++k) o1[k] = (short)hbits(tl[c * 65 + mb + 8 + k]);
  *(s16x8*)(WhT + (size_t)(n0 + c) * 4096 + m0 + mb) = o0;
  *(s16x8*)(WhT + (size_t)(n0 + c) * 4096 + m0 + mb + 8) = o1;
}

// grid (16 ih x 4 jh, 8 heads) = 512 blocks, 512 thr = 8 waves.
// Block: head h, rows i0b..+255 (wave = 32 rows = 2 row-tiles), j-slice 1024.
// f16 packed: t2 = pk_max(E2, pk_mul(r2,F2)) & mask2 -> f16 A-frag directly.
// Ring-4 counted-vmcnt prefetch; rolled chunk loop (fits L1i).
__global__ __launch_bounds__(512, 4) void k_attn(
    const uint32_t* __restrict__ mask32,
    const ushort* __restrict__ WhT,
    const ushort* __restrict__ EsT,
    const ushort* __restrict__ es2T,
    const float* __restrict__ rT,
    ushort* __restrict__ num,     // [4][4096][512] bf16
    float* __restrict__ lbuf) {   // [4][8][4096]
  __shared__ ushort tile[4][4096];       // 32 KB ring (f16 data)
  __shared__ uint32_t mask_s[256 * 33];  // 33.8 KB (stride 33: conflict-free)
  __shared__ uint32_t Es_s[512];         // 2 KB (f16 pairs)
  __shared__ uint32_t es2_s[512];        // 2 KB

  const int t = threadIdx.x;
  const int lane = t & 63, wv = t >> 6;
  const int l15 = lane & 15, lg = lane >> 4;
  const int h = blockIdx.y;
  const int jh = blockIdx.x & 3;
  const int ih = blockIdx.x >> 2;
  const int i0b = ih * 256;
  const int j0 = jh * 1024;

  // ---- stage Es/es2 (1024 f16 each = 128 uint4) ----
  if (t < 128) {
    ((uint4*)Es_s)[t] = ((const uint4*)EsT)[(h * 4096 + j0) / 8 + t];
  } else if (t < 256) {
    ((uint4*)es2_s)[t - 128] = ((const uint4*)es2T)[(h * 4096 + j0) / 8 + t - 128];
  }
  // ---- stage mask: 256 rows x 32 words; 2 threads/row x 64B ----
  {
    const int r = t >> 1, part = t & 1;
    const uint32_t* src = mask32 + (size_t)(i0b + r) * 128 + jh * 32 + part * 16;
    uint32_t* dst = &mask_s[r * 33 + part * 16];
#pragma unroll
    for (int k = 0; k < 4; ++k)
      *(int4*)(dst + k * 4) = *(const int4*)(src + k * 4);
  }
  // ---- per-wave pre-swizzled staging source (wave stages 8 cols) ----
  const int cg = (wv << 3) + (lane >> 3);       // col 0..63
  const int gg = (lane & 7) ^ (cg & 7);         // swizzled j-group
  const ushort* sbase = WhT + (size_t)(h * 64 + cg) * 4096 + j0 + gg * 8;

  // prologue: prefetch chunks 0..2 (syncthreads drains; also covers staging)
  gl_lds16(sbase, &tile[0][wv * 512]);
  gl_lds16(sbase + 64, &tile[1][wv * 512]);
  gl_lds16(sbase + 128, &tile[2][wv * 512]);
  __syncthreads();

  const int rloc = wv * 32 + l15;
  const float r0f = rT[h * 4096 + i0b + rloc];
  const float r1f = rT[h * 4096 + i0b + rloc + 16];
  const h2v r02 = {(_Float16)r0f, (_Float16)r0f};
  const h2v r12 = {(_Float16)r1f, (_Float16)r1f};

  f32x4 acc[2][4] = {};
  f32x4 accd0 = {}, accd1 = {};
  s16x8 bones;                                  // f16 B ones-column (col 0 = 1.0)
  {
    const short v = (l15 == 0) ? (short)0x3C00 : (short)0;
    bones[0] = v; bones[1] = v; bones[2] = v; bones[3] = v;
    bones[4] = v; bones[5] = v; bones[6] = v; bones[7] = v;
  }

#pragma unroll 1
  for (int c = 0; c < 16; ++c) {
    // counted wait: chunk c's load landed; 2 stay in flight (steady state)
    if (c < 14)       asm volatile("s_waitcnt vmcnt(2)" ::: "memory");
    else if (c == 14) asm volatile("s_waitcnt vmcnt(1)" ::: "memory");
    else              asm volatile("s_waitcnt vmcnt(0)" ::: "memory");
    __builtin_amdgcn_s_barrier();   // all waves: chunk c ready, compute(c-1) done
    if (c < 13) gl_lds16(sbase + (size_t)(c + 3) * 64, &tile[(c + 3) & 3][wv * 512]);
    const char* tb = (const char*)&tile[c & 3][0];
#pragma unroll
    for (int half = 0; half < 2; ++half) {
      const int jsub = half * 32;
      const uint4 e4 = *(const uint4*)&Es_s[c * 32 + (jsub >> 1) + lg * 4];
      const uint4 f4 = *(const uint4*)&es2_s[c * 32 + (jsub >> 1) + lg * 4];
      const uint32_t w0 = mask_s[rloc * 33 + c * 2 + half] >> (lg * 8);
      const uint32_t w1 = mask_s[(rloc + 16) * 33 + c * 2 + half] >> (lg * 8);
      s16x8 b[4];
#pragma unroll
      for (int ct = 0; ct < 4; ++ct) {
        const int col = ct * 16 + l15;
        b[ct] = *(const s16x8*)(tb + col * 128 + ((jsub * 2 + lg * 16) ^ ((col & 7) << 4)));
      }
      union { s16x8 v8; uint32_t u32[4]; } pa0, pa1;
#pragma unroll
      for (int q2 = 0; q2 < 4; ++q2) {
        const int q = q2 * 2;
        const h2v e2 = u2h2(((const uint32_t*)&e4)[q2]);
        const h2v f2 = u2h2(((const uint32_t*)&f4)[q2]);
        const h2v t0 = __builtin_elementwise_max(e2, r02 * f2);  // pk_mul+pk_max
        const h2v t1 = __builtin_elementwise_max(e2, r12 * f2);
        const uint32_t mk0 = (((w0 >> q) & 1u) | (((w0 >> q) & 2u) << 15)) * 0xFFFFu;
        const uint32_t mk1 = (((w1 >> q) & 1u) | (((w1 >> q) & 2u) << 15)) * 0xFFFFu;
        pa0.u32[q2] = mk0 & h22u(t0);
        pa1.u32[q2] = mk1 & h22u(t1);
      }
      accd0 = __builtin_amdgcn_mfma_f32_16x16x32_f16(pa0.v8, bones, accd0, 0, 0, 0);
      accd1 = __builtin_amdgcn_mfma_f32_16x16x32_f16(pa1.v8, bones, accd1, 0, 0, 0);
#pragma unroll
      for (int ct = 0; ct < 4; ++ct) {
        acc[0][ct] = __builtin_amdgcn_mfma_f32_16x16x32_f16(pa0.v8, b[ct], acc[0][ct], 0, 0, 0);
        acc[1][ct] = __builtin_amdgcn_mfma_f32_16x16x32_f16(pa1.v8, b[ct], acc[1][ct], 0, 0, 0);
      }
    }
  }

  // denominator partials: lanes l15==0 hold rows lg*4+r at col 0 of accd
  if (l15 == 0) {
    float* lb = &lbuf[((size_t)jh * 8 + h) * 4096 + i0b + rloc];  // rloc has l15=0
#pragma unroll
    for (int r = 0; r < 4; ++r) lb[lg * 4 + r] = accd0[r];
#pragma unroll
    for (int r = 0; r < 4; ++r) lb[16 + lg * 4 + r] = accd1[r];
  }
  ushort* np = num + (size_t)jh * 4096 * 512;
#pragma unroll
  for (int rs = 0; rs < 2; ++rs)
#pragma unroll
    for (int ct = 0; ct < 4; ++ct)
#pragma unroll
      for (int r = 0; r < 4; ++r)
        np[(size_t)(i0b + wv * 32 + rs * 16 + lg * 4 + r) * 512 + h * 64 + ct * 16 + l15] =
            (ushort)bf16b(acc[rs][ct][r]);
}

// 256 blocks x 512 thr; block = 16 rows, thread = 1 col. Writes hp bf16.
__global__ __launch_bounds__(512) void k_stats(const ushort* __restrict__ num,
                                               const float* __restrict__ lbuf,
                                               ushort* __restrict__ hpb,
                                               float* __restrict__ stats) {
  __shared__ float linv_s[128];
  const int t = threadIdx.x;
  const int r0 = blockIdx.x * 16;
  if (t < 128) {
    const int r = r0 + (t >> 3), hh = t & 7;
    float l = 0.f;
#pragma unroll
    for (int s = 0; s < 4; ++s) l += lbuf[((size_t)s * 8 + hh) * 4096 + r];
    linv_s[t] = 1.0f / l;
  }
  __syncthreads();
  const int c = t;
  const int hh = c >> 6;
  float s1 = 0.f, s2 = 0.f;
  for (int rr = 0; rr < 16; ++rr) {
    const int r = r0 + rr;
    float nsum = 0.f;
#pragma unroll
    for (int s = 0; s < 4; ++s)
      nsum += bf2f(num[(size_t)s * 4096 * 512 + (size_t)r * 512 + c]);
    const float v = nsum * linv_s[rr * 8 + hh];
    hpb[(size_t)r * 512 + c] = (ushort)bf16b(v);
    s1 += v; s2 += v * v;
  }
  atomicAdd(&stats[c], s1);
  atomicAdd(&stats[512 + c], s2);
}

// 1024 blocks x 256 thr; thread = 8 consecutive cols of one row. Reads hp bf16.
__global__ __launch_bounds__(256) void k_apply(const ushort* __restrict__ hpb,
                                               const float* __restrict__ stats,
                                               const float* __restrict__ gamma,
                                               const float* __restrict__ beta,
                                               float* __restrict__ out) {
  const size_t idx8 = ((size_t)blockIdx.x * 256 + threadIdx.x) * 8;
  const int c0 = (int)(idx8 & 511);
  s16x8 hv = *(const s16x8*)(hpb + idx8);
#pragma unroll
  for (int k = 0; k < 8; ++k) {
    const int cc = c0 + k;
    const float mean = stats[cc] * (1.f / 4096.f);
    const float var = stats[512 + cc] * (1.f / 4096.f) - mean * mean;
    const float v = bf2f((ushort)hv[k]);
    const float val = (v - mean) * rsqrtf(var + 1e-5f) * gamma[cc] + beta[cc];
    out[idx8 + k] = fmaxf(val, 0.f);
  }
}

extern "C" void kernel_launch(void* const* d_in, const int* in_sizes, int n_in,
                              void* d_out, int out_size, void* d_ws, size_t ws_size,
                              hipStream_t stream) {
  const float* x = (const float*)d_in[0];
  const int* adj = (const int*)d_in[1];
  const float* W = (const float*)d_in[2];
  const float* a = (const float*)d_in[3];
  const float* gamma = (const float*)d_in[4];
  const float* beta = (const float*)d_in[5];
  float* out = (float*)d_out;

  char* ws = (char*)d_ws;
  size_t off = 0;
  auto alloc = [&](size_t bytes) -> void* {
    void* p = ws + off;
    off += (bytes + 255) & ~(size_t)255;
    return p;
  };
  // persistent region (~11 MB)
  ushort* WhT   = (ushort*)alloc((size_t)512 * 4096 * 2);
  ushort* EsT   = (ushort*)alloc((size_t)8 * 4096 * 2);
  ushort* es2T  = (ushort*)alloc((size_t)8 * 4096 * 2);
  float*  rT    = (float*)alloc((size_t)8 * 4096 * 4);
  unsigned long long* maskw = (unsigned long long*)alloc((size_t)4096 * 64 * 8);
  float*  lbuf  = (float*)alloc((size_t)32 * 4096 * 4);
  ushort* hpb   = (ushort*)alloc((size_t)4096 * 512 * 2);
  float*  stats = (float*)alloc((size_t)1024 * 4);
  ushort* num   = (ushort*)alloc((size_t)4 * 4096 * 512 * 2);  // 16.8 MB
  // total ~28 MB

  hipLaunchKernelGGL(k_main, dim3(2560), dim3(256), 0, stream,
                     x, W, adj, a, maskw, stats, WhT, EsT, es2T, rT);
  hipLaunchKernelGGL(k_attn, dim3(64, 8), dim3(512), 0, stream,
                     (const uint32_t*)maskw, WhT, EsT, es2T, rT, num, lbuf);
  hipLaunchKernelGGL(k_stats, dim3(256), dim3(512), 0, stream, num, lbuf, hpb, stats);
  hipLaunchKernelGGL(k_apply, dim3(1024), dim3(256), 0, stream, hpb, stats, gamma, beta, out);
}

// Round 14
// 73.640 us; speedup vs baseline: 2.0356x; 2.0356x over previous
//
#include <hip/hip_runtime.h>
#include <hip/hip_bf16.h>
#include <hip/hip_fp16.h>
#include <stdint.h>

// GATv2-style layer, MI355X. 5 kernels (R12 structure, proven 75.2 us):
//  k_prep:    [blocks 0..2303] x,W fp32 -> bf16 ; [2304..4351] adj -> bitmask,
//             zero stats
//  k_gemm:    Wh = x @ W^T (bf16 MFMA, B-tile LDS-staged w/ XOR swizzle)
//             -> WhT f16 (LDS transpose) + factored-softmax arrays:
//             Es=exp2(a) f16, es2=exp2(0.2a) f16, r=exp2(-0.8b) f32.
//  k_attn:    fused masked-softmax numer/denom + PV MFMA, ALL f16 packed math:
//             t2 = pk_max(E2, pk_mul(r2, F2)) & mask2  -> directly the f16
//             A-frag word (no cvt). Row factor exp2(b_i) cancels in num/denom.
//             Mask decode via v_bfe_i32 x2 + v_perm_b32 (3 ops, no mul).
//             B-tile ring-4 via global_load_lds, counted vmcnt, rolled loop
//             (L1i — the R6-R9 51us wall).
//  k_stats:   column sums of h' = (sum num)/(sum accd) via atomics; hp bf16
//  k_apply:   read hp bf16, apply layernorm + relu
// num (16.8 MB, bf16, 4 j-slices) aliases xb/wb which are dead after k_gemm.

typedef __attribute__((ext_vector_type(4))) float f32x4;
typedef __attribute__((ext_vector_type(8))) short s16x8;
typedef __attribute__((ext_vector_type(2))) _Float16 h2v;

#define LOG2E 1.4426950408889634f

static __device__ __forceinline__ ushort f2bf(float f) {
  union { float f; uint32_t u; } v; v.f = f;
  uint32_t r = (v.u + 0x7FFFu + ((v.u >> 16) & 1u)) >> 16;  // RNE
  return (ushort)r;
}

static __device__ __forceinline__ short bf16b(float f) {
  __hip_bfloat16 h = __float2bfloat16(f);
  union { __hip_bfloat16 h; short s; } c; c.h = h;
  return c.s;
}

static __device__ __forceinline__ float bf2f(ushort u) {
  union { uint32_t u; float f; } c; c.u = ((uint32_t)u) << 16;
  return c.f;
}

static __device__ __forceinline__ ushort hbits(float f) {
  union { _Float16 h; ushort u; } c; c.h = (_Float16)f;
  return c.u;
}

static __device__ __forceinline__ h2v u2h2(uint32_t u) {
  union { uint32_t u; h2v h; } c; c.u = u; return c.h;
}
static __device__ __forceinline__ uint32_t h22u(h2v h) {
  union { uint32_t u; h2v h; } c; c.h = h; return c.u;
}

// bits q,q+1 of w -> {lo16,hi16} all-ones masks: bfe.i32 x2 + perm (3 VALU)
static __device__ __forceinline__ uint32_t mask2f16(uint32_t w, int q) {
#if __has_builtin(__builtin_amdgcn_sbfe) && __has_builtin(__builtin_amdgcn_perm)
  const uint32_t mlo = (uint32_t)__builtin_amdgcn_sbfe((int)w, q, 1);
  const uint32_t mhi = (uint32_t)__builtin_amdgcn_sbfe((int)w, q + 1, 1);
  return __builtin_amdgcn_perm(mhi, mlo, 0x07060100u);
#else
  return (((w >> q) & 1u) | (((w >> q) & 2u) << 15)) * 0xFFFFu;
#endif
}

// async global->LDS, 16B per lane; dest = wave-uniform base + lane*16
static __device__ __forceinline__ void gl_lds16(const ushort* g, ushort* l) {
  __builtin_amdgcn_global_load_lds(
      (const __attribute__((address_space(1))) unsigned int*)(g),
      (__attribute__((address_space(3))) unsigned int*)(l), 16, 0, 0);
}

// blocks 0..2303: convert x,W -> bf16. blocks 2304..4351: pack adj -> bits.
__global__ __launch_bounds__(256) void k_prep(const float* __restrict__ x,
                                              const float* __restrict__ W,
                                              const int* __restrict__ adj,
                                              ushort* __restrict__ xb,
                                              ushort* __restrict__ wb,
                                              unsigned long long* __restrict__ maskw,
                                              float* __restrict__ stats) {
  const int t = threadIdx.x;
  if (blockIdx.x < 2304) {
    const int idx = (blockIdx.x * 256 + t) * 4;
    const int NX = 4096 * 512;
    if (idx < NX) {
      float4 v = *(const float4*)(x + idx);
      ushort4 o; o.x = f2bf(v.x); o.y = f2bf(v.y); o.z = f2bf(v.z); o.w = f2bf(v.w);
      *(ushort4*)(xb + idx) = o;
    } else {
      const int k = idx - NX;
      float4 v = *(const float4*)(W + k);
      ushort4 o; o.x = f2bf(v.x); o.y = f2bf(v.y); o.z = f2bf(v.z); o.w = f2bf(v.w);
      *(ushort4*)(wb + k) = o;
    }
  } else {
    const int pb = blockIdx.x - 2304;
    if (pb == 0) {
      stats[t] = 0.f; stats[t + 256] = 0.f; stats[t + 512] = 0.f; stats[t + 768] = 0.f;
    }
    const size_t base = (size_t)pb * 8192;
    const int lane = t & 63;
#pragma unroll 4
    for (int it = 0; it < 32; ++it) {
      const size_t elem = base + it * 256 + t;
      unsigned long long b = __ballot(adj[elem] > 0);
      if (lane == 0) maskw[elem >> 6] = b;
    }
  }
}

// Per block: 64 rows (m0) x one head's 64 cols. K=512.
// B-tile (64 KB) LDS-staged via global_load_lds w/ pre-swizzled source.
// Epilogue: svec shfl reduce -> f16 factored-exp arrays; WhT f16 via transpose.
__global__ __launch_bounds__(256) void k_gemm(const ushort* __restrict__ xb,
                                              const ushort* __restrict__ wb,
                                              const float* __restrict__ a,
                                              ushort* __restrict__ WhT,
                                              ushort* __restrict__ EsT,
                                              ushort* __restrict__ es2T,
                                              float* __restrict__ rT) {
  __shared__ ushort bt[64 * 512];        // 64 KB; later aliased as f32 tl[64*65]
  float* tl = (float*)bt;
  const int lane = threadIdx.x & 63;
  const int wv = threadIdx.x >> 6;       // 4 waves: M sub-tiles
  const int l15 = lane & 15, lg = lane >> 4;
  const int m0 = blockIdx.x * 64;
  const int h = blockIdx.y;
  const int n0 = h * 64;

  // ---- stage B: wave wv stages cols it*4+wv (1 KB each, swizzled source) ----
#pragma unroll
  for (int it = 0; it < 16; ++it) {
    const int col = it * 4 + wv;
    const ushort* src = wb + (size_t)(n0 + col) * 512 + (lane ^ (col & 7)) * 8;
    gl_lds16(src, &bt[col * 512]);
  }
  __syncthreads();

  const ushort* ap = xb + (size_t)(m0 + wv * 16 + l15) * 512 + lg * 8;
  f32x4 acc[4] = {};
  for (int k0 = 0; k0 < 512; k0 += 32) {
    s16x8 av = *(const s16x8*)(ap + k0);
#pragma unroll
    for (int ct = 0; ct < 4; ++ct) {
      const int col = ct * 16 + l15;
      s16x8 b = *(const s16x8*)((const char*)bt + col * 1024 +
                                (((k0 + lg * 8) * 2) ^ ((col & 7) << 4)));
      acc[ct] = __builtin_amdgcn_mfma_f32_16x16x32_bf16(av, b, acc[ct], 0, 0, 0);
    }
  }
  // ---- svec: s[row] = sum_col acc*a_slice, reduce over 16 l15 lanes ----
  float aS[4], aD[4];
#pragma unroll
  for (int ct = 0; ct < 4; ++ct) {
    aS[ct] = a[ct * 16 + l15];
    aD[ct] = a[64 + ct * 16 + l15];
  }
#pragma unroll
  for (int r = 0; r < 4; ++r) {
    float s1 = acc[0][r] * aS[0] + acc[1][r] * aS[1] + acc[2][r] * aS[2] + acc[3][r] * aS[3];
    float s2 = acc[0][r] * aD[0] + acc[1][r] * aD[1] + acc[2][r] * aD[2] + acc[3][r] * aD[3];
#pragma unroll
    for (int off = 1; off < 16; off <<= 1) {
      s1 += __shfl_xor(s1, off);
      s2 += __shfl_xor(s2, off);
    }
    if (l15 == 0) {
      const int row = m0 + wv * 16 + lg * 4 + r;
      const float aa = s1 * LOG2E;   // src (j-role), log2 domain
      const float bb = s2 * LOG2E;   // dst (i-role)
      EsT[h * 4096 + row]  = hbits(__builtin_amdgcn_exp2f(aa));
      es2T[h * 4096 + row] = hbits(__builtin_amdgcn_exp2f(0.2f * aa));
      rT[h * 4096 + row]   = __builtin_amdgcn_exp2f(-0.8f * bb);
    }
  }
  // ---- transposed f16 store: WhT[n0+c][m0+m] (tl aliases bt; barrier first) ----
  __syncthreads();
#pragma unroll
  for (int ct = 0; ct < 4; ++ct)
#pragma unroll
    for (int r = 0; r < 4; ++r)
      tl[(ct * 16 + l15) * 65 + wv * 16 + lg * 4 + r] = acc[ct][r];
  __syncthreads();
  const int c = threadIdx.x >> 2, mb = (threadIdx.x & 3) * 16;
  s16x8 o0, o1;
#pragma unroll
  for (int k = 0; k < 8; ++k) o0[k] = (short)hbits(tl[c * 65 + mb + k]);
#pragma unroll
  for (int k = 0; k < 8; ++k) o1[k] = (short)hbits(tl[c * 65 + mb + 8 + k]);
  *(s16x8*)(WhT + (size_t)(n0 + c) * 4096 + m0 + mb) = o0;
  *(s16x8*)(WhT + (size_t)(n0 + c) * 4096 + m0 + mb + 8) = o1;
}

// grid (16 ih x 4 jh, 8 heads) = 512 blocks, 512 thr = 8 waves.
// Block: head h, rows i0b..+255 (wave = 32 rows = 2 row-tiles), j-slice 1024.
// f16 packed: t2 = pk_max(E2, pk_mul(r2,F2)) & mask2 -> f16 A-frag directly.
// Ring-4 counted-vmcnt prefetch; rolled chunk loop (fits L1i).
__global__ __launch_bounds__(512, 4) void k_attn(
    const uint32_t* __restrict__ mask32,
    const ushort* __restrict__ WhT,
    const ushort* __restrict__ EsT,
    const ushort* __restrict__ es2T,
    const float* __restrict__ rT,
    ushort* __restrict__ num,     // [4][4096][512] bf16
    float* __restrict__ lbuf) {   // [4][8][4096]
  __shared__ ushort tile[4][4096];       // 32 KB ring (f16 data)
  __shared__ uint32_t mask_s[256 * 33];  // 33.8 KB (stride 33: conflict-free)
  __shared__ uint32_t Es_s[512];         // 2 KB (f16 pairs)
  __shared__ uint32_t es2_s[512];        // 2 KB

  const int t = threadIdx.x;
  const int lane = t & 63, wv = t >> 6;
  const int l15 = lane & 15, lg = lane >> 4;
  const int h = blockIdx.y;
  const int jh = blockIdx.x & 3;
  const int ih = blockIdx.x >> 2;
  const int i0b = ih * 256;
  const int j0 = jh * 1024;

  // ---- stage Es/es2 (1024 f16 each = 128 uint4) ----
  if (t < 128) {
    ((uint4*)Es_s)[t] = ((const uint4*)EsT)[(h * 4096 + j0) / 8 + t];
  } else if (t < 256) {
    ((uint4*)es2_s)[t - 128] = ((const uint4*)es2T)[(h * 4096 + j0) / 8 + t - 128];
  }
  // ---- stage mask: 256 rows x 32 words; 2 threads/row x 64B ----
  {
    const int r = t >> 1, part = t & 1;
    const uint32_t* src = mask32 + (size_t)(i0b + r) * 128 + jh * 32 + part * 16;
    uint32_t* dst = &mask_s[r * 33 + part * 16];
#pragma unroll
    for (int k = 0; k < 4; ++k)
      *(int4*)(dst + k * 4) = *(const int4*)(src + k * 4);
  }
  // ---- per-wave pre-swizzled staging source (wave stages 8 cols) ----
  const int cg = (wv << 3) + (lane >> 3);       // col 0..63
  const int gg = (lane & 7) ^ (cg & 7);         // swizzled j-group
  const ushort* sbase = WhT + (size_t)(h * 64 + cg) * 4096 + j0 + gg * 8;

  // prologue: prefetch chunks 0..2 (syncthreads drains; also covers staging)
  gl_lds16(sbase, &tile[0][wv * 512]);
  gl_lds16(sbase + 64, &tile[1][wv * 512]);
  gl_lds16(sbase + 128, &tile[2][wv * 512]);
  __syncthreads();

  const int rloc = wv * 32 + l15;
  const float r0f = rT[h * 4096 + i0b + rloc];
  const float r1f = rT[h * 4096 + i0b + rloc + 16];
  const h2v r02 = {(_Float16)r0f, (_Float16)r0f};
  const h2v r12 = {(_Float16)r1f, (_Float16)r1f};

  f32x4 acc[2][4] = {};
  f32x4 accd0 = {}, accd1 = {};
  s16x8 bones;                                  // f16 B ones-column (col 0 = 1.0)
  {
    const short v = (l15 == 0) ? (short)0x3C00 : (short)0;
    bones[0] = v; bones[1] = v; bones[2] = v; bones[3] = v;
    bones[4] = v; bones[5] = v; bones[6] = v; bones[7] = v;
  }

#pragma unroll 1
  for (int c = 0; c < 16; ++c) {
    // counted wait: chunk c's load landed; 2 stay in flight (steady state)
    if (c < 14)       asm volatile("s_waitcnt vmcnt(2)" ::: "memory");
    else if (c == 14) asm volatile("s_waitcnt vmcnt(1)" ::: "memory");
    else              asm volatile("s_waitcnt vmcnt(0)" ::: "memory");
    __builtin_amdgcn_s_barrier();   // all waves: chunk c ready, compute(c-1) done
    if (c < 13) gl_lds16(sbase + (size_t)(c + 3) * 64, &tile[(c + 3) & 3][wv * 512]);
    const char* tb = (const char*)&tile[c & 3][0];
#pragma unroll
    for (int half = 0; half < 2; ++half) {
      const int jsub = half * 32;
      const uint4 e4 = *(const uint4*)&Es_s[c * 32 + (jsub >> 1) + lg * 4];
      const uint4 f4 = *(const uint4*)&es2_s[c * 32 + (jsub >> 1) + lg * 4];
      const uint32_t w0 = mask_s[rloc * 33 + c * 2 + half] >> (lg * 8);
      const uint32_t w1 = mask_s[(rloc + 16) * 33 + c * 2 + half] >> (lg * 8);
      s16x8 b[4];
#pragma unroll
      for (int ct = 0; ct < 4; ++ct) {
        const int col = ct * 16 + l15;
        b[ct] = *(const s16x8*)(tb + col * 128 + ((jsub * 2 + lg * 16) ^ ((col & 7) << 4)));
      }
      union { s16x8 v8; uint32_t u32[4]; } pa0, pa1;
#pragma unroll
      for (int q2 = 0; q2 < 4; ++q2) {
        const int q = q2 * 2;
        const h2v e2 = u2h2(((const uint32_t*)&e4)[q2]);
        const h2v f2 = u2h2(((const uint32_t*)&f4)[q2]);
        const h2v t0 = __builtin_elementwise_max(e2, r02 * f2);  // pk_mul+pk_max
        const h2v t1 = __builtin_elementwise_max(e2, r12 * f2);
        pa0.u32[q2] = mask2f16(w0, q) & h22u(t0);
        pa1.u32[q2] = mask2f16(w1, q) & h22u(t1);
      }
      accd0 = __builtin_amdgcn_mfma_f32_16x16x32_f16(pa0.v8, bones, accd0, 0, 0, 0);
      accd1 = __builtin_amdgcn_mfma_f32_16x16x32_f16(pa1.v8, bones, accd1, 0, 0, 0);
#pragma unroll
      for (int ct = 0; ct < 4; ++ct) {
        acc[0][ct] = __builtin_amdgcn_mfma_f32_16x16x32_f16(pa0.v8, b[ct], acc[0][ct], 0, 0, 0);
        acc[1][ct] = __builtin_amdgcn_mfma_f32_16x16x32_f16(pa1.v8, b[ct], acc[1][ct], 0, 0, 0);
      }
    }
  }

  // denominator partials: lanes l15==0 hold rows lg*4+r at col 0 of accd
  if (l15 == 0) {
    float* lb = &lbuf[((size_t)jh * 8 + h) * 4096 + i0b + rloc];  // rloc has l15=0
#pragma unroll
    for (int r = 0; r < 4; ++r) lb[lg * 4 + r] = accd0[r];
#pragma unroll
    for (int r = 0; r < 4; ++r) lb[16 + lg * 4 + r] = accd1[r];
  }
  ushort* np = num + (size_t)jh * 4096 * 512;
#pragma unroll
  for (int rs = 0; rs < 2; ++rs)
#pragma unroll
    for (int ct = 0; ct < 4; ++ct)
#pragma unroll
      for (int r = 0; r < 4; ++r)
        np[(size_t)(i0b + wv * 32 + rs * 16 + lg * 4 + r) * 512 + h * 64 + ct * 16 + l15] =
            (ushort)bf16b(acc[rs][ct][r]);
}

// 256 blocks x 512 thr; block = 16 rows, thread = 1 col. Writes hp bf16.
__global__ __launch_bounds__(512) void k_stats(const ushort* __restrict__ num,
                                               const float* __restrict__ lbuf,
                                               ushort* __restrict__ hpb,
                                               float* __restrict__ stats) {
  __shared__ float linv_s[128];
  const int t = threadIdx.x;
  const int r0 = blockIdx.x * 16;
  if (t < 128) {
    const int r = r0 + (t >> 3), hh = t & 7;
    float l = 0.f;
#pragma unroll
    for (int s = 0; s < 4; ++s) l += lbuf[((size_t)s * 8 + hh) * 4096 + r];
    linv_s[t] = 1.0f / l;
  }
  __syncthreads();
  const int c = t;
  const int hh = c >> 6;
  float s1 = 0.f, s2 = 0.f;
  for (int rr = 0; rr < 16; ++rr) {
    const int r = r0 + rr;
    float nsum = 0.f;
#pragma unroll
    for (int s = 0; s < 4; ++s)
      nsum += bf2f(num[(size_t)s * 4096 * 512 + (size_t)r * 512 + c]);
    const float v = nsum * linv_s[rr * 8 + hh];
    hpb[(size_t)r * 512 + c] = (ushort)bf16b(v);
    s1 += v; s2 += v * v;
  }
  atomicAdd(&stats[c], s1);
  atomicAdd(&stats[512 + c], s2);
}

// 1024 blocks x 256 thr; thread = 8 consecutive cols of one row. Reads hp bf16.
__global__ __launch_bounds__(256) void k_apply(const ushort* __restrict__ hpb,
                                               const float* __restrict__ stats,
                                               const float* __restrict__ gamma,
                                               const float* __restrict__ beta,
                                               float* __restrict__ out) {
  const size_t idx8 = ((size_t)blockIdx.x * 256 + threadIdx.x) * 8;
  const int c0 = (int)(idx8 & 511);
  s16x8 hv = *(const s16x8*)(hpb + idx8);
#pragma unroll
  for (int k = 0; k < 8; ++k) {
    const int cc = c0 + k;
    const float mean = stats[cc] * (1.f / 4096.f);
    const float var = stats[512 + cc] * (1.f / 4096.f) - mean * mean;
    const float v = bf2f((ushort)hv[k]);
    const float val = (v - mean) * rsqrtf(var + 1e-5f) * gamma[cc] + beta[cc];
    out[idx8 + k] = fmaxf(val, 0.f);
  }
}

extern "C" void kernel_launch(void* const* d_in, const int* in_sizes, int n_in,
                              void* d_out, int out_size, void* d_ws, size_t ws_size,
                              hipStream_t stream) {
  const float* x = (const float*)d_in[0];
  const int* adj = (const int*)d_in[1];
  const float* W = (const float*)d_in[2];
  const float* a = (const float*)d_in[3];
  const float* gamma = (const float*)d_in[4];
  const float* beta = (const float*)d_in[5];
  float* out = (float*)d_out;

  char* ws = (char*)d_ws;
  size_t off = 0;
  auto alloc = [&](size_t bytes) -> void* {
    void* p = ws + off;
    off += (bytes + 255) & ~(size_t)255;
    return p;
  };
  // persistent region (~11 MB)
  ushort* WhT   = (ushort*)alloc((size_t)512 * 4096 * 2);
  ushort* EsT   = (ushort*)alloc((size_t)8 * 4096 * 2);
  ushort* es2T  = (ushort*)alloc((size_t)8 * 4096 * 2);
  float*  rT    = (float*)alloc((size_t)8 * 4096 * 4);
  unsigned long long* maskw = (unsigned long long*)alloc((size_t)4096 * 64 * 8);
  float*  lbuf  = (float*)alloc((size_t)32 * 4096 * 4);
  ushort* hpb   = (ushort*)alloc((size_t)4096 * 512 * 2);
  float*  stats = (float*)alloc((size_t)1024 * 4);
  // overlay region: xb+wb (gemm inputs) aliased by num (attn output)
  const size_t ov = off;
  ushort* xb = (ushort*)(ws + ov);
  ushort* wb = (ushort*)(ws + ov + (size_t)4096 * 512 * 2);
  ushort* num = (ushort*)(ws + ov);           // [4][4096][512] bf16 = 16.8 MB
  // total ~28 MB

  hipLaunchKernelGGL(k_prep, dim3(4352), dim3(256), 0, stream,
                     x, W, adj, xb, wb, maskw, stats);
  hipLaunchKernelGGL(k_gemm, dim3(64, 8), dim3(256), 0, stream, xb, wb, a,
                     WhT, EsT, es2T, rT);
  hipLaunchKernelGGL(k_attn, dim3(64, 8), dim3(512), 0, stream,
                     (const uint32_t*)maskw, WhT, EsT, es2T, rT, num, lbuf);
  hipLaunchKernelGGL(k_stats, dim3(256), dim3(512), 0, stream, num, lbuf, hpb, stats);
  hipLaunchKernelGGL(k_apply, dim3(1024), dim3(256), 0, stream, hpb, stats, gamma, beta, out);
}